// Round 1
// 90.151 us; speedup vs baseline: 1.0780x; 1.0780x over previous
//
#include <hip/hip_runtime.h>

// SimplifyLoss: Chamfer-style loss, fused pair pass + single reduce.
// preds: [8, 2048, 3] f32, gts: [8, 8192, 3] f32, out: scalar f32.
//
// d[b,i,j] = ||gt_i - pred_j||^2 = gg_i + (pp_j - 2*dot(g_i,p_j))
// loss = mean_{b,j} colmin + mean_{b,i} rowmin + mean_b max_j colmin
//
// K1 pair_k: grid 1024 = (b, gtblk of 128 gts, pred-half of 1024). ALL 1024
//   preds staged once in LDS as (-2x,-2y,-2z,pp) float4, padded idx=q+(q>>3)
//   so the wave's 4 tx-groups hit distinct banks -> conflict-free b128
//   broadcasts, and the 8-step main loop has NO barriers. Thread = (tx
//   pred-slot 0..15, ty gt-group 0..15): 8 gts fixed in regs (v2f packed for
//   v_pk_fma_f32), 8 preds/step from LDS. Row-mins in regs all kernel;
//   col-mins per step reduced over ty (lane bits 0..3) via SPLIT butterfly:
//   each stage halves the j-set (4+2+1+1 shuffles vs naive 32), lane ty<8
//   ends holding the full col-min for pred j=ty of its tx group.
// K2 red_k: grid (8,9). y<8: colmin over 64 gtblks -> chunk sum+max ->
//   atomicAdd(acc)/atomicMax(bmax). y==8: row sum of min(2 halves). 72nd
//   block writes out[0] = acc + mean_b(bmax). No init kernel (pair_k blk 0
//   zero-inits ws accumulators; safe via kernel-boundary ordering).

#define BB 8
#define MM 2048
#define NN 8192

typedef float v2f __attribute__((ext_vector_type(2)));

__device__ __forceinline__ int pad_idx(int q) { return q + (q >> 3); }

__global__ __launch_bounds__(256, 4) void pair_k(const float* __restrict__ preds,
                                                 const float* __restrict__ gts,
                                                 float* __restrict__ rowpart,
                                                 float* __restrict__ colpart,
                                                 float* __restrict__ acc,
                                                 unsigned* __restrict__ bmax,
                                                 unsigned* __restrict__ cnt) {
    const int blk   = blockIdx.x;
    const int b     = blk >> 7;
    const int gtblk = (blk >> 1) & 63;
    const int ph    = blk & 1;          // pred half (0/1)
    const int tid   = threadIdx.x;
    const int tx    = tid >> 4;         // pred slot group 0..15
    const int ty    = tid & 15;         // gt group 0..15 (= lane bits 0..3)

    if (blk == 0 && tid < 16) {
        if (tid == 0) { acc[0] = 0.0f; cnt[0] = 0u; }
        if (tid < 8) bmax[tid] = 0u;    // 0-bits == 0.0f, identity for max >= 0
    }

    // 1024 preds as (-2x,-2y,-2z,pp), padded every 8 entries (18.4 KB).
    __shared__ float4 sp4[1152];

    // Stage all preds of this half once: 4 preds (12 floats, 3x b128) per thread.
    {
        const float4* pg = (const float4*)(preds + (size_t)(b * MM + ph * 1024) * 3);
        float4 r0 = pg[tid * 3 + 0], r1 = pg[tid * 3 + 1], r2 = pg[tid * 3 + 2];
        float x[4], y[4], z[4];
        x[0] = r0.x; y[0] = r0.y; z[0] = r0.z;
        x[1] = r0.w; y[1] = r1.x; z[1] = r1.y;
        x[2] = r1.z; y[2] = r1.w; z[2] = r2.x;
        x[3] = r2.y; y[3] = r2.z; z[3] = r2.w;
#pragma unroll
        for (int k = 0; k < 4; ++k) {
            const int q = tid * 4 + k;
            sp4[pad_idx(q)] = make_float4(-2.0f * x[k], -2.0f * y[k], -2.0f * z[k],
                                          fmaf(x[k], x[k], fmaf(y[k], y[k], z[k] * z[k])));
        }
    }

    // My 8 gts (24 contiguous floats, 6x b128) -> v2f packed + ||g||^2.
    v2f gx2[4], gy2[4], gz2[4], gg2[4], rmin2[4];
    {
        const float4* g4 = (const float4*)(gts + (size_t)(b * NN + gtblk * 128 + ty * 8) * 3);
        float4 a0 = g4[0], a1 = g4[1], a2 = g4[2], a3 = g4[3], a4 = g4[4], a5 = g4[5];
        float gx[8], gy[8], gz[8];
        gx[0] = a0.x; gy[0] = a0.y; gz[0] = a0.z;
        gx[1] = a0.w; gy[1] = a1.x; gz[1] = a1.y;
        gx[2] = a1.z; gy[2] = a1.w; gz[2] = a2.x;
        gx[3] = a2.y; gy[3] = a2.z; gz[3] = a2.w;
        gx[4] = a3.x; gy[4] = a3.y; gz[4] = a3.z;
        gx[5] = a3.w; gy[5] = a4.x; gz[5] = a4.y;
        gx[6] = a4.z; gy[6] = a4.w; gz[6] = a5.x;
        gx[7] = a5.y; gy[7] = a5.z; gz[7] = a5.w;
#pragma unroll
        for (int ip = 0; ip < 4; ++ip) {
            gx2[ip] = (v2f){gx[2 * ip], gx[2 * ip + 1]};
            gy2[ip] = (v2f){gy[2 * ip], gy[2 * ip + 1]};
            gz2[ip] = (v2f){gz[2 * ip], gz[2 * ip + 1]};
            gg2[ip] = __builtin_elementwise_fma(gx2[ip], gx2[ip],
                      __builtin_elementwise_fma(gy2[ip], gy2[ip], gz2[ip] * gz2[ip]));
            rmin2[ip] = (v2f){3.4e38f, 3.4e38f};
        }
    }

    const bool b0 = (ty & 1) != 0;
    const bool b1 = (ty & 2) != 0;
    const bool b2 = (ty & 4) != 0;
    float* cbase = colpart + ((size_t)b * 64 + gtblk) * MM + ph * 1024 + tx * 8;

    __syncthreads();   // preds staged; no barriers needed inside main loop

    for (int step = 0; step < 8; ++step) {
        v2f cmin2[8];
#pragma unroll
        for (int j = 0; j < 8; ++j) cmin2[j] = (v2f){3.4e38f, 3.4e38f};

#pragma unroll
        for (int j = 0; j < 8; ++j) {
            const float4 p = sp4[pad_idx(step * 128 + tx * 8 + j)];
            const v2f px2 = (v2f){p.x, p.x};
            const v2f py2 = (v2f){p.y, p.y};
            const v2f pz2 = (v2f){p.z, p.z};
            const v2f pp2 = (v2f){p.w, p.w};
#pragma unroll
            for (int ip = 0; ip < 4; ++ip) {
                v2f t = __builtin_elementwise_fma(gx2[ip], px2, pp2);
                t     = __builtin_elementwise_fma(gy2[ip], py2, t);
                t     = __builtin_elementwise_fma(gz2[ip], pz2, t);
                v2f d = gg2[ip] + t;
                rmin2[ip] = __builtin_elementwise_min(rmin2[ip], d);
                cmin2[j]  = __builtin_elementwise_min(cmin2[j], d);
            }
        }

        // Collapse pack-pair, then split-butterfly over ty (lane bits 0..3):
        // each stage halves the j-set, so shuffle count is 4+2+1+1 = 8
        // (vs naive 32). After stage 3, lane holds the 16-lane min for
        // j = (ty&7); stage 4 folds the remaining bit3 duplicate pair.
        float cmin[8];
#pragma unroll
        for (int j = 0; j < 8; ++j) cmin[j] = fminf(cmin2[j].x, cmin2[j].y);

        float n1[4];
#pragma unroll
        for (int k = 0; k < 4; ++k) {
            float send = b0 ? cmin[2 * k] : cmin[2 * k + 1];
            float keep = b0 ? cmin[2 * k + 1] : cmin[2 * k];
            n1[k] = fminf(keep, __shfl_xor(send, 1, 64));
        }
        float n2[2];
#pragma unroll
        for (int k = 0; k < 2; ++k) {
            float send = b1 ? n1[2 * k] : n1[2 * k + 1];
            float keep = b1 ? n1[2 * k + 1] : n1[2 * k];
            n2[k] = fminf(keep, __shfl_xor(send, 2, 64));
        }
        {
            float send = b2 ? n2[0] : n2[1];
            float keep = b2 ? n2[1] : n2[0];
            float v = fminf(keep, __shfl_xor(send, 4, 64));
            v = fminf(v, __shfl_xor(v, 8, 64));
            // lane ty (<8) holds full col-min for pred j = ty of this tx group;
            // per wave: 32 active lanes store 32 contiguous floats (128 B).
            if (ty < 8) cbase[step * 128 + ty] = v;
        }
    }

    // Row-min cross-tx reduce; reuse sp4 as scratch (2048 floats needed).
    float* red = (float*)sp4;
    __syncthreads();   // all waves done reading sp4 as preds
#pragma unroll
    for (int ip = 0; ip < 4; ++ip) {
        red[tx * 128 + ty * 8 + 2 * ip]     = rmin2[ip].x;
        red[tx * 128 + ty * 8 + 2 * ip + 1] = rmin2[ip].y;
    }
    __syncthreads();
    if (tid < 128) {
        float m = red[tid];
#pragma unroll
        for (int k = 1; k < 16; ++k) m = fminf(m, red[k * 128 + tid]);
        rowpart[((size_t)b * 2 + ph) * NN + gtblk * 128 + tid] = m;
    }
}

__global__ __launch_bounds__(256) void red_k(const float* __restrict__ rowpart,
                                             const float* __restrict__ colpart,
                                             float* __restrict__ acc,
                                             unsigned* __restrict__ bmax,
                                             unsigned* __restrict__ cnt,
                                             float* __restrict__ out) {
    const int b = blockIdx.x, y = blockIdx.y, tid = threadIdx.x;
    __shared__ float a1[4], a2[4];

    if (y < 8) {
        const int p = y * 256 + tid;
        const float* cp = colpart + (size_t)b * 64 * MM + p;
        float m = 3.4e38f;
#pragma unroll 8
        for (int g = 0; g < 64; ++g) m = fminf(m, cp[(size_t)g * MM]);
        float s = m, mx = m;
#pragma unroll
        for (int o = 32; o > 0; o >>= 1) {
            s += __shfl_down(s, o, 64);
            mx = fmaxf(mx, __shfl_down(mx, o, 64));
        }
        const int w = tid >> 6, lane = tid & 63;
        if (lane == 0) { a1[w] = s; a2[w] = mx; }
        __syncthreads();
        if (tid == 0) {
            float cs = a1[0] + a1[1] + a1[2] + a1[3];
            float cm = fmaxf(fmaxf(a2[0], a2[1]), fmaxf(a2[2], a2[3]));
            atomicAdd(acc, cs / (float)(BB * MM));          // loss_1 contribution
            atomicMax(&bmax[b], __float_as_uint(cm));       // per-batch col max
        }
    } else {
        const float* r = rowpart + (size_t)b * 2 * NN;
        float s = 0.0f;
        for (int i = tid; i < NN; i += 256) s += fminf(r[i], r[NN + i]);
#pragma unroll
        for (int o = 32; o > 0; o >>= 1) s += __shfl_down(s, o, 64);
        const int w = tid >> 6, lane = tid & 63;
        if (lane == 0) a1[w] = s;
        __syncthreads();
        if (tid == 0)
            atomicAdd(acc, (a1[0] + a1[1] + a1[2] + a1[3]) / (float)(BB * NN)); // loss_2
    }

    if (tid == 0) {
        __threadfence();
        unsigned old = atomicAdd(cnt, 1u);
        if (old == 71u) {                    // last of 72 blocks
            __threadfence();
            float a = atomicAdd(acc, 0.0f);  // fetch final sum
            float mm = 0.0f;
#pragma unroll
            for (int bb = 0; bb < 8; ++bb)
                mm += __uint_as_float(atomicMax(&bmax[bb], 0u));
            out[0] = a + mm / (float)BB;     // + loss_m
        }
    }
}

extern "C" void kernel_launch(void* const* d_in, const int* in_sizes, int n_in,
                              void* d_out, int out_size, void* d_ws, size_t ws_size,
                              hipStream_t stream) {
    const float* preds = (const float*)d_in[0];
    const float* gts   = (const float*)d_in[1];
    float* out = (float*)d_out;

    // ws (floats): rowpart[2*8*8192] | colpart[8*64*2048] | acc[1] | bmax[8] | cnt[1]
    float* rowpart = (float*)d_ws;
    float* colpart = rowpart + (size_t)2 * BB * NN;
    float* acc     = colpart + (size_t)BB * 64 * MM;
    unsigned* bmax = (unsigned*)(acc + 1);
    unsigned* cnt  = bmax + 8;

    pair_k<<<1024, 256, 0, stream>>>(preds, gts, rowpart, colpart, acc, bmax, cnt);
    red_k<<<dim3(BB, 9), 256, 0, stream>>>(rowpart, colpart, acc, bmax, cnt, out);
}

// Round 2
// 89.854 us; speedup vs baseline: 1.0816x; 1.0033x over previous
//
#include <hip/hip_runtime.h>

// SimplifyLoss: Chamfer-style loss, fused pair pass + single reduce.
// preds: [8, 2048, 3] f32, gts: [8, 8192, 3] f32, out: scalar f32.
//
// d[b,i,j] = ||gt_i - pred_j||^2 = gg_i + (pp_j - 2*dot(g_i,p_j))
// loss = mean_{b,j} colmin + mean_{b,i} rowmin + mean_b max_j colmin
//
// K1 pair_k: grid 1024 = (b, gtblk of 128 gts, pred-half of 1024). ALL 1024
//   preds staged once in LDS as (-2x,-2y,-2z,pp) float4, padded idx=q+(q>>3)
//   so the wave's 4 tx-groups hit distinct banks -> conflict-free b128
//   broadcasts, and the 8-step main loop has NO barriers. Thread = (tx
//   pred-slot 0..15, ty gt-group 0..15): 8 gts fixed in regs (v2f packed for
//   v_pk_fma_f32), 8 preds/step from LDS, processed in j-PAIRS so both row
//   and col accumulators use v_min3_f32 (3 instr/pair vs 4 with v_min):
//     rmin.x = min3(rmin.x, da.x, db.x)   // two preds into one row acc
//     cmin[j] = min3(cmin[j], d.x, d.y)   // two gts into one scalar col acc
//   Col-mins per step reduced over ty (lane bits 0..3) via SPLIT butterfly
//   (4+2+1+1 shuffles), lane ty<8 stores col-min for pred j=ty of tx group.
// K2 red_k: grid (8,9). y<8: colmin over 64 gtblks -> chunk sum+max ->
//   atomicAdd(acc)/atomicMax(bmax). y==8: row sum of min(2 halves). 72nd
//   block writes out[0] = acc + mean_b(bmax). No init kernel (pair_k blk 0
//   zero-inits ws accumulators; safe via kernel-boundary ordering).

#define BB 8
#define MM 2048
#define NN 8192

typedef float v2f __attribute__((ext_vector_type(2)));

__device__ __forceinline__ int pad_idx(int q) { return q + (q >> 3); }

__device__ __forceinline__ float min3f(float a, float b, float c) {
    float d;
    asm("v_min3_f32 %0, %1, %2, %3" : "=v"(d) : "v"(a), "v"(b), "v"(c));
    return d;
}

__global__ __launch_bounds__(256, 4) void pair_k(const float* __restrict__ preds,
                                                 const float* __restrict__ gts,
                                                 float* __restrict__ rowpart,
                                                 float* __restrict__ colpart,
                                                 float* __restrict__ acc,
                                                 unsigned* __restrict__ bmax,
                                                 unsigned* __restrict__ cnt) {
    const int blk   = blockIdx.x;
    const int b     = blk >> 7;
    const int gtblk = (blk >> 1) & 63;
    const int ph    = blk & 1;          // pred half (0/1)
    const int tid   = threadIdx.x;
    const int tx    = tid >> 4;         // pred slot group 0..15
    const int ty    = tid & 15;         // gt group 0..15 (= lane bits 0..3)

    if (blk == 0 && tid < 16) {
        if (tid == 0) { acc[0] = 0.0f; cnt[0] = 0u; }
        if (tid < 8) bmax[tid] = 0u;    // 0-bits == 0.0f, identity for max >= 0
    }

    // 1024 preds as (-2x,-2y,-2z,pp), padded every 8 entries (18.4 KB).
    __shared__ float4 sp4[1152];

    // Stage all preds of this half once: 4 preds (12 floats, 3x b128) per thread.
    {
        const float4* pg = (const float4*)(preds + (size_t)(b * MM + ph * 1024) * 3);
        float4 r0 = pg[tid * 3 + 0], r1 = pg[tid * 3 + 1], r2 = pg[tid * 3 + 2];
        float x[4], y[4], z[4];
        x[0] = r0.x; y[0] = r0.y; z[0] = r0.z;
        x[1] = r0.w; y[1] = r1.x; z[1] = r1.y;
        x[2] = r1.z; y[2] = r1.w; z[2] = r2.x;
        x[3] = r2.y; y[3] = r2.z; z[3] = r2.w;
#pragma unroll
        for (int k = 0; k < 4; ++k) {
            const int q = tid * 4 + k;
            sp4[pad_idx(q)] = make_float4(-2.0f * x[k], -2.0f * y[k], -2.0f * z[k],
                                          fmaf(x[k], x[k], fmaf(y[k], y[k], z[k] * z[k])));
        }
    }

    // My 8 gts (24 contiguous floats, 6x b128) -> v2f packed + ||g||^2.
    v2f gx2[4], gy2[4], gz2[4], gg2[4];
    float rminx[4], rminy[4];
    {
        const float4* g4 = (const float4*)(gts + (size_t)(b * NN + gtblk * 128 + ty * 8) * 3);
        float4 a0 = g4[0], a1 = g4[1], a2 = g4[2], a3 = g4[3], a4 = g4[4], a5 = g4[5];
        float gx[8], gy[8], gz[8];
        gx[0] = a0.x; gy[0] = a0.y; gz[0] = a0.z;
        gx[1] = a0.w; gy[1] = a1.x; gz[1] = a1.y;
        gx[2] = a1.z; gy[2] = a1.w; gz[2] = a2.x;
        gx[3] = a2.y; gy[3] = a2.z; gz[3] = a2.w;
        gx[4] = a3.x; gy[4] = a3.y; gz[4] = a3.z;
        gx[5] = a3.w; gy[5] = a4.x; gz[5] = a4.y;
        gx[6] = a4.z; gy[6] = a4.w; gz[6] = a5.x;
        gx[7] = a5.y; gy[7] = a5.z; gz[7] = a5.w;
#pragma unroll
        for (int ip = 0; ip < 4; ++ip) {
            gx2[ip] = (v2f){gx[2 * ip], gx[2 * ip + 1]};
            gy2[ip] = (v2f){gy[2 * ip], gy[2 * ip + 1]};
            gz2[ip] = (v2f){gz[2 * ip], gz[2 * ip + 1]};
            gg2[ip] = __builtin_elementwise_fma(gx2[ip], gx2[ip],
                      __builtin_elementwise_fma(gy2[ip], gy2[ip], gz2[ip] * gz2[ip]));
            rminx[ip] = 3.4e38f;
            rminy[ip] = 3.4e38f;
        }
    }

    const bool b0 = (ty & 1) != 0;
    const bool b1 = (ty & 2) != 0;
    const bool b2 = (ty & 4) != 0;
    float* cbase = colpart + ((size_t)b * 64 + gtblk) * MM + ph * 1024 + tx * 8;

    __syncthreads();   // preds staged; no barriers needed inside main loop

    for (int step = 0; step < 8; ++step) {
        float cmin[8];
#pragma unroll
        for (int j = 0; j < 8; ++j) cmin[j] = 3.4e38f;

#pragma unroll
        for (int j = 0; j < 8; j += 2) {
            const float4 pa = sp4[pad_idx(step * 128 + tx * 8 + j)];
            const float4 pb = sp4[pad_idx(step * 128 + tx * 8 + j + 1)];
            const v2f pax2 = (v2f){pa.x, pa.x}, pay2 = (v2f){pa.y, pa.y};
            const v2f paz2 = (v2f){pa.z, pa.z}, pap2 = (v2f){pa.w, pa.w};
            const v2f pbx2 = (v2f){pb.x, pb.x}, pby2 = (v2f){pb.y, pb.y};
            const v2f pbz2 = (v2f){pb.z, pb.z}, pbp2 = (v2f){pb.w, pb.w};
#pragma unroll
            for (int ip = 0; ip < 4; ++ip) {
                v2f ta = __builtin_elementwise_fma(gx2[ip], pax2, pap2);
                ta     = __builtin_elementwise_fma(gy2[ip], pay2, ta);
                ta     = __builtin_elementwise_fma(gz2[ip], paz2, ta);
                const v2f da = gg2[ip] + ta;
                v2f tb = __builtin_elementwise_fma(gx2[ip], pbx2, pbp2);
                tb     = __builtin_elementwise_fma(gy2[ip], pby2, tb);
                tb     = __builtin_elementwise_fma(gz2[ip], pbz2, tb);
                const v2f db = gg2[ip] + tb;
                rminx[ip]   = min3f(rminx[ip], da.x, db.x);
                rminy[ip]   = min3f(rminy[ip], da.y, db.y);
                cmin[j]     = min3f(cmin[j], da.x, da.y);
                cmin[j + 1] = min3f(cmin[j + 1], db.x, db.y);
            }
        }

        // Split butterfly over ty (lane bits 0..3): each stage halves the
        // j-set (4+2+1+1 shuffles). After stage 3, lane holds the 16-lane
        // min for j=(ty&7); stage 4 folds the bit3 duplicate pair.
        float n1[4];
#pragma unroll
        for (int k = 0; k < 4; ++k) {
            float send = b0 ? cmin[2 * k] : cmin[2 * k + 1];
            float keep = b0 ? cmin[2 * k + 1] : cmin[2 * k];
            n1[k] = fminf(keep, __shfl_xor(send, 1, 64));
        }
        float n2[2];
#pragma unroll
        for (int k = 0; k < 2; ++k) {
            float send = b1 ? n1[2 * k] : n1[2 * k + 1];
            float keep = b1 ? n1[2 * k + 1] : n1[2 * k];
            n2[k] = fminf(keep, __shfl_xor(send, 2, 64));
        }
        {
            float send = b2 ? n2[0] : n2[1];
            float keep = b2 ? n2[1] : n2[0];
            float v = fminf(keep, __shfl_xor(send, 4, 64));
            v = fminf(v, __shfl_xor(v, 8, 64));
            // lane ty (<8) holds full col-min for pred j = ty of this tx group;
            // per wave: 32 active lanes store 32 contiguous floats (128 B).
            if (ty < 8) cbase[step * 128 + ty] = v;
        }
    }

    // Row-min cross-tx reduce; reuse sp4 as scratch (2048 floats needed).
    float* red = (float*)sp4;
    __syncthreads();   // all waves done reading sp4 as preds
#pragma unroll
    for (int ip = 0; ip < 4; ++ip) {
        red[tx * 128 + ty * 8 + 2 * ip]     = rminx[ip];
        red[tx * 128 + ty * 8 + 2 * ip + 1] = rminy[ip];
    }
    __syncthreads();
    if (tid < 128) {
        float m = red[tid];
#pragma unroll
        for (int k = 1; k < 16; ++k) m = fminf(m, red[k * 128 + tid]);
        rowpart[((size_t)b * 2 + ph) * NN + gtblk * 128 + tid] = m;
    }
}

__global__ __launch_bounds__(256) void red_k(const float* __restrict__ rowpart,
                                             const float* __restrict__ colpart,
                                             float* __restrict__ acc,
                                             unsigned* __restrict__ bmax,
                                             unsigned* __restrict__ cnt,
                                             float* __restrict__ out) {
    const int b = blockIdx.x, y = blockIdx.y, tid = threadIdx.x;
    __shared__ float a1[4], a2[4];

    if (y < 8) {
        const int p = y * 256 + tid;
        const float* cp = colpart + (size_t)b * 64 * MM + p;
        float m = 3.4e38f;
#pragma unroll 8
        for (int g = 0; g < 64; ++g) m = fminf(m, cp[(size_t)g * MM]);
        float s = m, mx = m;
#pragma unroll
        for (int o = 32; o > 0; o >>= 1) {
            s += __shfl_down(s, o, 64);
            mx = fmaxf(mx, __shfl_down(mx, o, 64));
        }
        const int w = tid >> 6, lane = tid & 63;
        if (lane == 0) { a1[w] = s; a2[w] = mx; }
        __syncthreads();
        if (tid == 0) {
            float cs = a1[0] + a1[1] + a1[2] + a1[3];
            float cm = fmaxf(fmaxf(a2[0], a2[1]), fmaxf(a2[2], a2[3]));
            atomicAdd(acc, cs / (float)(BB * MM));          // loss_1 contribution
            atomicMax(&bmax[b], __float_as_uint(cm));       // per-batch col max
        }
    } else {
        const float* r = rowpart + (size_t)b * 2 * NN;
        float s = 0.0f;
        for (int i = tid; i < NN; i += 256) s += fminf(r[i], r[NN + i]);
#pragma unroll
        for (int o = 32; o > 0; o >>= 1) s += __shfl_down(s, o, 64);
        const int w = tid >> 6, lane = tid & 63;
        if (lane == 0) a1[w] = s;
        __syncthreads();
        if (tid == 0)
            atomicAdd(acc, (a1[0] + a1[1] + a1[2] + a1[3]) / (float)(BB * NN)); // loss_2
    }

    if (tid == 0) {
        __threadfence();
        unsigned old = atomicAdd(cnt, 1u);
        if (old == 71u) {                    // last of 72 blocks
            __threadfence();
            float a = atomicAdd(acc, 0.0f);  // fetch final sum
            float mm = 0.0f;
#pragma unroll
            for (int bb = 0; bb < 8; ++bb)
                mm += __uint_as_float(atomicMax(&bmax[bb], 0u));
            out[0] = a + mm / (float)BB;     // + loss_m
        }
    }
}

extern "C" void kernel_launch(void* const* d_in, const int* in_sizes, int n_in,
                              void* d_out, int out_size, void* d_ws, size_t ws_size,
                              hipStream_t stream) {
    const float* preds = (const float*)d_in[0];
    const float* gts   = (const float*)d_in[1];
    float* out = (float*)d_out;

    // ws (floats): rowpart[2*8*8192] | colpart[8*64*2048] | acc[1] | bmax[8] | cnt[1]
    float* rowpart = (float*)d_ws;
    float* colpart = rowpart + (size_t)2 * BB * NN;
    float* acc     = colpart + (size_t)BB * 64 * MM;
    unsigned* bmax = (unsigned*)(acc + 1);
    unsigned* cnt  = bmax + 8;

    pair_k<<<1024, 256, 0, stream>>>(preds, gts, rowpart, colpart, acc, bmax, cnt);
    red_k<<<dim3(BB, 9), 256, 0, stream>>>(rowpart, colpart, acc, bmax, cnt, out);
}

// Round 3
// 80.824 us; speedup vs baseline: 1.2024x; 1.1117x over previous
//
#include <hip/hip_runtime.h>

// SimplifyLoss: Chamfer-style loss, fused pair pass + single reduce.
// preds: [8, 2048, 3] f32, gts: [8, 8192, 3] f32, out: scalar f32.
//
// d[b,i,j] = ||gt_i - pred_j||^2 = gg_i + (pp_j - 2*dot(g_i,p_j))
// loss = mean_{b,j} colmin + mean_{b,i} rowmin + mean_b max_j colmin
//
// K1 pair_k: grid 1024 = (b, gtblk of 128 gts, pred-half of 1024). ALL 1024
//   preds staged once in LDS as (-2x,-2y,-2z,pp) float4, padded idx=q+(q>>3)
//   so the wave's 4 tx-groups hit distinct banks -> conflict-free b128
//   broadcasts, and the 8-step main loop has NO barriers. Thread = (tx
//   pred-slot 0..15, ty gt-group 0..15): 8 gts fixed in regs (v2f packed for
//   v_pk_fma_f32), 8 preds/step from LDS, processed in j-PAIRS so both row
//   and col accumulators use v_min3_f32 (main loop is at the exact-f32 VALU
//   floor: 2.0 pk-FMA + 1.0 min3 per pair). Col-mins per step reduced over
//   ty via SPLIT butterfly (4+2+1+1 shuffles), lane ty<8 stores col-min for
//   pred j=ty of its tx group.
// K2 red_k: grid (8,10), latency-optimized (was the latency-bound tail):
//   y<8: colmin over 64 gtblks with 32 loads in flight (unroll 8 x 4-wide,
//   min3 tree) -> chunk sum+max -> atomicAdd(acc)/atomicMax(bmax).
//   y==8/9: each handles half the row sum (more blocks, unroll 8).
//   80th block writes out[0] = acc + mean_b(bmax). No init kernel (pair_k
//   blk 0 zero-inits ws accumulators; safe via kernel-boundary ordering).

#define BB 8
#define MM 2048
#define NN 8192

typedef float v2f __attribute__((ext_vector_type(2)));

__device__ __forceinline__ int pad_idx(int q) { return q + (q >> 3); }

__device__ __forceinline__ float min3f(float a, float b, float c) {
    float d;
    asm("v_min3_f32 %0, %1, %2, %3" : "=v"(d) : "v"(a), "v"(b), "v"(c));
    return d;
}

__global__ __launch_bounds__(256, 4) void pair_k(const float* __restrict__ preds,
                                                 const float* __restrict__ gts,
                                                 float* __restrict__ rowpart,
                                                 float* __restrict__ colpart,
                                                 float* __restrict__ acc,
                                                 unsigned* __restrict__ bmax,
                                                 unsigned* __restrict__ cnt) {
    const int blk   = blockIdx.x;
    const int b     = blk >> 7;
    const int gtblk = (blk >> 1) & 63;
    const int ph    = blk & 1;          // pred half (0/1)
    const int tid   = threadIdx.x;
    const int tx    = tid >> 4;         // pred slot group 0..15
    const int ty    = tid & 15;         // gt group 0..15 (= lane bits 0..3)

    if (blk == 0 && tid < 16) {
        if (tid == 0) { acc[0] = 0.0f; cnt[0] = 0u; }
        if (tid < 8) bmax[tid] = 0u;    // 0-bits == 0.0f, identity for max >= 0
    }

    // 1024 preds as (-2x,-2y,-2z,pp), padded every 8 entries (18.4 KB).
    __shared__ float4 sp4[1152];

    // Stage all preds of this half once: 4 preds (12 floats, 3x b128) per thread.
    {
        const float4* pg = (const float4*)(preds + (size_t)(b * MM + ph * 1024) * 3);
        float4 r0 = pg[tid * 3 + 0], r1 = pg[tid * 3 + 1], r2 = pg[tid * 3 + 2];
        float x[4], y[4], z[4];
        x[0] = r0.x; y[0] = r0.y; z[0] = r0.z;
        x[1] = r0.w; y[1] = r1.x; z[1] = r1.y;
        x[2] = r1.z; y[2] = r1.w; z[2] = r2.x;
        x[3] = r2.y; y[3] = r2.z; z[3] = r2.w;
#pragma unroll
        for (int k = 0; k < 4; ++k) {
            const int q = tid * 4 + k;
            sp4[pad_idx(q)] = make_float4(-2.0f * x[k], -2.0f * y[k], -2.0f * z[k],
                                          fmaf(x[k], x[k], fmaf(y[k], y[k], z[k] * z[k])));
        }
    }

    // My 8 gts (24 contiguous floats, 6x b128) -> v2f packed + ||g||^2.
    v2f gx2[4], gy2[4], gz2[4], gg2[4];
    float rminx[4], rminy[4];
    {
        const float4* g4 = (const float4*)(gts + (size_t)(b * NN + gtblk * 128 + ty * 8) * 3);
        float4 a0 = g4[0], a1 = g4[1], a2 = g4[2], a3 = g4[3], a4 = g4[4], a5 = g4[5];
        float gx[8], gy[8], gz[8];
        gx[0] = a0.x; gy[0] = a0.y; gz[0] = a0.z;
        gx[1] = a0.w; gy[1] = a1.x; gz[1] = a1.y;
        gx[2] = a1.z; gy[2] = a1.w; gz[2] = a2.x;
        gx[3] = a2.y; gy[3] = a2.z; gz[3] = a2.w;
        gx[4] = a3.x; gy[4] = a3.y; gz[4] = a3.z;
        gx[5] = a3.w; gy[5] = a4.x; gz[5] = a4.y;
        gx[6] = a4.z; gy[6] = a4.w; gz[6] = a5.x;
        gx[7] = a5.y; gy[7] = a5.z; gz[7] = a5.w;
#pragma unroll
        for (int ip = 0; ip < 4; ++ip) {
            gx2[ip] = (v2f){gx[2 * ip], gx[2 * ip + 1]};
            gy2[ip] = (v2f){gy[2 * ip], gy[2 * ip + 1]};
            gz2[ip] = (v2f){gz[2 * ip], gz[2 * ip + 1]};
            gg2[ip] = __builtin_elementwise_fma(gx2[ip], gx2[ip],
                      __builtin_elementwise_fma(gy2[ip], gy2[ip], gz2[ip] * gz2[ip]));
            rminx[ip] = 3.4e38f;
            rminy[ip] = 3.4e38f;
        }
    }

    const bool b0 = (ty & 1) != 0;
    const bool b1 = (ty & 2) != 0;
    const bool b2 = (ty & 4) != 0;
    float* cbase = colpart + ((size_t)b * 64 + gtblk) * MM + ph * 1024 + tx * 8;

    __syncthreads();   // preds staged; no barriers needed inside main loop

    for (int step = 0; step < 8; ++step) {
        float cmin[8];
#pragma unroll
        for (int j = 0; j < 8; ++j) cmin[j] = 3.4e38f;

#pragma unroll
        for (int j = 0; j < 8; j += 2) {
            const float4 pa = sp4[pad_idx(step * 128 + tx * 8 + j)];
            const float4 pb = sp4[pad_idx(step * 128 + tx * 8 + j + 1)];
            const v2f pax2 = (v2f){pa.x, pa.x}, pay2 = (v2f){pa.y, pa.y};
            const v2f paz2 = (v2f){pa.z, pa.z}, pap2 = (v2f){pa.w, pa.w};
            const v2f pbx2 = (v2f){pb.x, pb.x}, pby2 = (v2f){pb.y, pb.y};
            const v2f pbz2 = (v2f){pb.z, pb.z}, pbp2 = (v2f){pb.w, pb.w};
#pragma unroll
            for (int ip = 0; ip < 4; ++ip) {
                v2f ta = __builtin_elementwise_fma(gx2[ip], pax2, pap2);
                ta     = __builtin_elementwise_fma(gy2[ip], pay2, ta);
                ta     = __builtin_elementwise_fma(gz2[ip], paz2, ta);
                const v2f da = gg2[ip] + ta;
                v2f tb = __builtin_elementwise_fma(gx2[ip], pbx2, pbp2);
                tb     = __builtin_elementwise_fma(gy2[ip], pby2, tb);
                tb     = __builtin_elementwise_fma(gz2[ip], pbz2, tb);
                const v2f db = gg2[ip] + tb;
                rminx[ip]   = min3f(rminx[ip], da.x, db.x);
                rminy[ip]   = min3f(rminy[ip], da.y, db.y);
                cmin[j]     = min3f(cmin[j], da.x, da.y);
                cmin[j + 1] = min3f(cmin[j + 1], db.x, db.y);
            }
        }

        // Split butterfly over ty (lane bits 0..3): each stage halves the
        // j-set (4+2+1+1 shuffles). After stage 3, lane holds the 16-lane
        // min for j=(ty&7); stage 4 folds the bit3 duplicate pair.
        float n1[4];
#pragma unroll
        for (int k = 0; k < 4; ++k) {
            float send = b0 ? cmin[2 * k] : cmin[2 * k + 1];
            float keep = b0 ? cmin[2 * k + 1] : cmin[2 * k];
            n1[k] = fminf(keep, __shfl_xor(send, 1, 64));
        }
        float n2[2];
#pragma unroll
        for (int k = 0; k < 2; ++k) {
            float send = b1 ? n1[2 * k] : n1[2 * k + 1];
            float keep = b1 ? n1[2 * k + 1] : n1[2 * k];
            n2[k] = fminf(keep, __shfl_xor(send, 2, 64));
        }
        {
            float send = b2 ? n2[0] : n2[1];
            float keep = b2 ? n2[1] : n2[0];
            float v = fminf(keep, __shfl_xor(send, 4, 64));
            v = fminf(v, __shfl_xor(v, 8, 64));
            // lane ty (<8) holds full col-min for pred j = ty of this tx group;
            // per wave: 32 active lanes store 32 contiguous floats (128 B).
            if (ty < 8) cbase[step * 128 + ty] = v;
        }
    }

    // Row-min cross-tx reduce; reuse sp4 as scratch (2048 floats needed).
    float* red = (float*)sp4;
    __syncthreads();   // all waves done reading sp4 as preds
#pragma unroll
    for (int ip = 0; ip < 4; ++ip) {
        red[tx * 128 + ty * 8 + 2 * ip]     = rminx[ip];
        red[tx * 128 + ty * 8 + 2 * ip + 1] = rminy[ip];
    }
    __syncthreads();
    if (tid < 128) {
        float m = red[tid];
#pragma unroll
        for (int k = 1; k < 16; ++k) m = fminf(m, red[k * 128 + tid]);
        rowpart[((size_t)b * 2 + ph) * NN + gtblk * 128 + tid] = m;
    }
}

__global__ __launch_bounds__(256) void red_k(const float* __restrict__ rowpart,
                                             const float* __restrict__ colpart,
                                             float* __restrict__ acc,
                                             unsigned* __restrict__ bmax,
                                             unsigned* __restrict__ cnt,
                                             float* __restrict__ out) {
    const int b = blockIdx.x, y = blockIdx.y, tid = threadIdx.x;
    __shared__ float a1[4], a2[4];

    if (y < 8) {
        // col-min over 64 gtblk partials for pred p. Latency-optimized:
        // 4 explicit loads per unrolled iter x unroll 8 = 32 loads in
        // flight (2 latency exposures vs 8 with the old unroll-8 chain).
        const int p = y * 256 + tid;
        const float* cp = colpart + (size_t)b * 64 * MM + p;
        float m = 3.4e38f;
#pragma unroll 8
        for (int g = 0; g < 64; g += 4) {
            float x0 = cp[(size_t)(g + 0) * MM];
            float x1 = cp[(size_t)(g + 1) * MM];
            float x2 = cp[(size_t)(g + 2) * MM];
            float x3 = cp[(size_t)(g + 3) * MM];
            m = min3f(m, min3f(x0, x1, x2), x3);
        }
        float s = m, mx = m;
#pragma unroll
        for (int o = 32; o > 0; o >>= 1) {
            s += __shfl_down(s, o, 64);
            mx = fmaxf(mx, __shfl_down(mx, o, 64));
        }
        const int w = tid >> 6, lane = tid & 63;
        if (lane == 0) { a1[w] = s; a2[w] = mx; }
        __syncthreads();
        if (tid == 0) {
            float cs = a1[0] + a1[1] + a1[2] + a1[3];
            float cm = fmaxf(fmaxf(a2[0], a2[1]), fmaxf(a2[2], a2[3]));
            atomicAdd(acc, cs / (float)(BB * MM));          // loss_1 contribution
            atomicMax(&bmax[b], __float_as_uint(cm));       // per-batch col max
        }
    } else {
        // row sum of min(2 halves); y==8 covers [0,NN/2), y==9 covers rest.
        const float* r = rowpart + (size_t)b * 2 * NN + (y - 8) * (NN / 2);
        float s = 0.0f;
#pragma unroll 8
        for (int i = tid; i < NN / 2; i += 256) s += fminf(r[i], r[NN + i]);
#pragma unroll
        for (int o = 32; o > 0; o >>= 1) s += __shfl_down(s, o, 64);
        const int w = tid >> 6, lane = tid & 63;
        if (lane == 0) a1[w] = s;
        __syncthreads();
        if (tid == 0)
            atomicAdd(acc, (a1[0] + a1[1] + a1[2] + a1[3]) / (float)(BB * NN)); // loss_2
    }

    if (tid == 0) {
        __threadfence();
        unsigned old = atomicAdd(cnt, 1u);
        if (old == 79u) {                    // last of 80 blocks
            __threadfence();
            float a = atomicAdd(acc, 0.0f);  // fetch final sum
            float mm = 0.0f;
#pragma unroll
            for (int bb = 0; bb < 8; ++bb)
                mm += __uint_as_float(atomicMax(&bmax[bb], 0u));
            out[0] = a + mm / (float)BB;     // + loss_m
        }
    }
}

extern "C" void kernel_launch(void* const* d_in, const int* in_sizes, int n_in,
                              void* d_out, int out_size, void* d_ws, size_t ws_size,
                              hipStream_t stream) {
    const float* preds = (const float*)d_in[0];
    const float* gts   = (const float*)d_in[1];
    float* out = (float*)d_out;

    // ws (floats): rowpart[2*8*8192] | colpart[8*64*2048] | acc[1] | bmax[8] | cnt[1]
    float* rowpart = (float*)d_ws;
    float* colpart = rowpart + (size_t)2 * BB * NN;
    float* acc     = colpart + (size_t)BB * 64 * MM;
    unsigned* bmax = (unsigned*)(acc + 1);
    unsigned* cnt  = bmax + 8;

    pair_k<<<1024, 256, 0, stream>>>(preds, gts, rowpart, colpart, acc, bmax, cnt);
    red_k<<<dim3(BB, 10), 256, 0, stream>>>(rowpart, colpart, acc, bmax, cnt, out);
}